// Round 5
// baseline (521.312 us; speedup 1.0000x reference)
//
#include <hip/hip_runtime.h>

#define NRES 768
#define CPAIR 128
#define CMSA 256

// 16-lane rotate-reduce step via DPP (row_ror:N within each 16-lane row).
template <int CTRL>
__device__ __forceinline__ float dpp_rot_add(float v) {
    const int r = __builtin_amdgcn_update_dpp(
        0, __float_as_int(v), CTRL, 0xF, 0xF, true);
    return v + __int_as_float(r);
}

// pair_kernel: one block (256 threads = 4 waves) handles 256 consecutive pairs
// within one row i. Grid = 768 rows x 3 segments.
//
// R5: explicit 2-stage software pipeline. pk indices prefetched 2 iterations
// ahead (LDS read never blocks the dependent w_rel load); x / w_rel global
// loads prefetched one A/B-pair ahead into named register sets. Stores plain
// float4 (R4 A/B showed NT stores cost 15 us).
__global__ __launch_bounds__(256) void pair_kernel(
    const int* __restrict__ aatype,
    const int* __restrict__ residue_index,
    const int* __restrict__ asym_id,
    const int* __restrict__ entity_id,
    const int* __restrict__ sym_id,
    const float* __restrict__ prev_pos,
    const float* __restrict__ prev_pair,
    const float* __restrict__ w_dgram,
    const float* __restrict__ b_dgram,
    const float* __restrict__ g_pair,
    const float* __restrict__ bt_pair,
    const float* __restrict__ w_rel,
    const float* __restrict__ b_rel,
    float* __restrict__ out_pair)
{
    __shared__ float Dtab[16][128];
    __shared__ float Etab[6][128];
    __shared__ unsigned short packs[256];

    const int tid = threadIdx.x;
    const int bx  = blockIdx.x;
    const int i   = bx / 3;                 // magic-mul div
    const int seg = bx - i * 3;
    const int j0  = seg * 256;

    // ---- stage distogram table (row 0 = zeros for bin==-1) ----
    for (int idx = tid; idx < 16 * 128; idx += 256) {
        const int r = idx >> 7, c = idx & 127;
        Dtab[r][c] = (r == 0) ? 0.0f : w_dgram[(r - 1) * 128 + c];
    }
    // ---- stage entity/chain table with constant bias vector folded in ----
    for (int idx = tid; idx < 6 * 128; idx += 256) {
        const int r = idx >> 7, c = idx & 127;
        const float cv = bt_pair[c] + b_dgram[c] + b_rel[c];
        const float wc = w_rel[(67 + r) * 128 + c];
        Etab[r][c] = cv + ((r < 5) ? (w_rel[66 * 128 + c] + wc) : wc);
    }

    // ---- per-pair packed indices: thread tid -> pair (i, j0+tid) ----
    {
        const int j  = j0 + tid;
        const int ai = (aatype[i] == 7) ? 1 : 3;   // GLY -> CA else CB
        const int aj = (aatype[j] == 7) ? 1 : 3;
        const float* pi = prev_pos + ((long)i * 37 + ai) * 3;
        const float* pj = prev_pos + ((long)j * 37 + aj) * 3;
        const float dx = pi[0] - pj[0];
        const float dy = pi[1] - pj[1];
        const float dz = pi[2] - pj[2];
        const float d2 = dx * dx + dy * dy + dz * dz;

        int bin = -1;
        #pragma unroll
        for (int b = 0; b < 15; ++b) {
            const float lo = 3.25f + 1.25f * (float)b;
            const float l2 = lo * lo;
            const float hi = lo + 1.25f;
            const float u2 = (b == 14) ? 1e8f : hi * hi;
            if (d2 > l2 && d2 < u2) bin = b;       // strict, matches reference
        }

        const bool asame = asym_id[i] == asym_id[j];
        int off = residue_index[i] - residue_index[j] + 32;
        off = min(max(off, 0), 64);
        const int p = asame ? off : 65;

        const bool esame = entity_id[i] == entity_id[j];
        int ch = sym_id[i] - sym_id[j] + 2;
        ch = min(max(ch, 0), 4);
        const int eidx = esame ? ch : 5;

        packs[tid] = (unsigned short)((bin + 1) | (p << 4) | (eidx << 11));
    }

    // ---- persistent per-lane channel vectors ----
    const int lane = tid & 63;
    const int wid  = tid >> 6;
    const int g    = lane >> 4;
    const int t    = lane & 15;
    const int c0   = t * 4;
    const int c1   = c0 + 64;

    const float4 gp0 = *(const float4*)(g_pair + c0);
    const float4 gp1 = *(const float4*)(g_pair + c1);

    __syncthreads();

    const float* rowp = prev_pair + ((long)i * NRES + j0) * CPAIR;
    float*       outp = out_pair + ((long)i * NRES + j0) * CPAIR;

    const int pb = (wid << 6) | g;          // pair(k) = pb + 4k

    auto COMPUTE = [&](unsigned int pk, const float4 x0, const float4 x1,
                       const float4 w0, const float4 w1, int kk) {
        const int bidx = pk & 15;
        const int eidx = (pk >> 11) & 7;
        const float4 d0 = *(const float4*)(&Dtab[bidx][c0]);
        const float4 d1 = *(const float4*)(&Dtab[bidx][c1]);
        const float4 e0 = *(const float4*)(&Etab[eidx][c0]);
        const float4 e1 = *(const float4*)(&Etab[eidx][c1]);

        float s = ((x0.x + x0.y) + (x0.z + x0.w)) + ((x1.x + x1.y) + (x1.z + x1.w));
        float q = ((x0.x * x0.x + x0.y * x0.y) + (x0.z * x0.z + x0.w * x0.w)) +
                  ((x1.x * x1.x + x1.y * x1.y) + (x1.z * x1.z + x1.w * x1.w));
        s = dpp_rot_add<0x121>(s); q = dpp_rot_add<0x121>(q);  // ror 1
        s = dpp_rot_add<0x122>(s); q = dpp_rot_add<0x122>(q);  // ror 2
        s = dpp_rot_add<0x124>(s); q = dpp_rot_add<0x124>(q);  // ror 4
        s = dpp_rot_add<0x128>(s); q = dpp_rot_add<0x128>(q);  // ror 8

        const float mu = s * (1.0f / 128.0f);
        const float var = q * (1.0f / 128.0f) - mu * mu;
        const float rstd = rsqrtf(var + 1e-5f);

        float4 o0, o1;
        o0.x = (x0.x - mu) * rstd * gp0.x + (d0.x + w0.x + e0.x);
        o0.y = (x0.y - mu) * rstd * gp0.y + (d0.y + w0.y + e0.y);
        o0.z = (x0.z - mu) * rstd * gp0.z + (d0.z + w0.z + e0.z);
        o0.w = (x0.w - mu) * rstd * gp0.w + (d0.w + w0.w + e0.w);
        o1.x = (x1.x - mu) * rstd * gp1.x + (d1.x + w1.x + e1.x);
        o1.y = (x1.y - mu) * rstd * gp1.y + (d1.y + w1.y + e1.y);
        o1.z = (x1.z - mu) * rstd * gp1.z + (d1.z + w1.z + e1.z);
        o1.w = (x1.w - mu) * rstd * gp1.w + (d1.w + w1.w + e1.w);

        float* op = outp + (long)(pb + (kk << 2)) * CPAIR;
        *(float4*)(op + c0) = o0;
        *(float4*)(op + c1) = o1;
    };

    // ---- prologue: pk for k=0..3; x/w for k=0,1 ----
    unsigned int pkA = packs[pb];
    unsigned int pkB = packs[pb + 4];
    unsigned int pkC = packs[pb + 8];
    unsigned int pkD = packs[pb + 12];
    float4 xA0, xA1, xB0, xB1, wA0, wA1, wB0, wB1;
    {
        const float* xpA = rowp + (long)pb * CPAIR;
        xA0 = *(const float4*)(xpA + c0); xA1 = *(const float4*)(xpA + c1);
        const float* xpB = rowp + (long)(pb + 4) * CPAIR;
        xB0 = *(const float4*)(xpB + c0); xB1 = *(const float4*)(xpB + c1);
        const float* wrA = w_rel + ((pkA >> 4) & 127) * 128;
        wA0 = *(const float4*)(wrA + c0); wA1 = *(const float4*)(wrA + c1);
        const float* wrB = w_rel + ((pkB >> 4) & 127) * 128;
        wB0 = *(const float4*)(wrB + c0); wB1 = *(const float4*)(wrB + c1);
    }

    for (int k = 0; k < 16; k += 2) {
        float4 yA0, yA1, yB0, yB1, vA0, vA1, vB0, vB1;
        unsigned int pkE = 0, pkF = 0;
        if (k + 2 < 16) {
            // issue next-stage loads BEFORE any compute of this stage
            const float* xpA = rowp + (long)(pb + ((k + 2) << 2)) * CPAIR;
            yA0 = *(const float4*)(xpA + c0); yA1 = *(const float4*)(xpA + c1);
            const float* xpB = rowp + (long)(pb + ((k + 3) << 2)) * CPAIR;
            yB0 = *(const float4*)(xpB + c0); yB1 = *(const float4*)(xpB + c1);
            const float* wrA = w_rel + ((pkC >> 4) & 127) * 128;
            vA0 = *(const float4*)(wrA + c0); vA1 = *(const float4*)(wrA + c1);
            const float* wrB = w_rel + ((pkD >> 4) & 127) * 128;
            vB0 = *(const float4*)(wrB + c0); vB1 = *(const float4*)(wrB + c1);
            if (k + 4 < 16) {
                pkE = packs[pb + ((k + 4) << 2)];
                pkF = packs[pb + ((k + 5) << 2)];
            }
        } else {
            yA0 = yA1 = yB0 = yB1 = make_float4(0.f, 0.f, 0.f, 0.f);
            vA0 = vA1 = vB0 = vB1 = make_float4(0.f, 0.f, 0.f, 0.f);
        }

        COMPUTE(pkA, xA0, xA1, wA0, wA1, k);
        COMPUTE(pkB, xB0, xB1, wB0, wB1, k + 1);

        pkA = pkC; pkB = pkD; pkC = pkE; pkD = pkF;
        xA0 = yA0; xA1 = yA1; xB0 = yB0; xB1 = yB1;
        wA0 = vA0; wA1 = vA1; wB0 = vB0; wB1 = vB1;
    }
}

// One wave64 per residue row; lane l holds channels 4l..4l+3 (float4).
__global__ __launch_bounds__(256) void msa_kernel(
    const float* __restrict__ prev_msa,
    const float* __restrict__ g_msa,
    const float* __restrict__ bt_msa,
    float* __restrict__ out_msa)
{
    const int lane = threadIdx.x & 63;
    const int row = (int)((blockIdx.x * blockDim.x + threadIdx.x) >> 6);
    if (row >= NRES) return;

    const int c = lane * 4;
    const long base = (long)row * CMSA + c;
    const float4 x = *(const float4*)(prev_msa + base);

    float s = (x.x + x.y) + (x.z + x.w);
    #pragma unroll
    for (int m = 32; m >= 1; m >>= 1) s += __shfl_xor(s, m);
    const float mu = s * (1.0f / 256.0f);

    const float a0 = x.x - mu, a1 = x.y - mu, a2 = x.z - mu, a3 = x.w - mu;
    float v = (a0 * a0 + a1 * a1) + (a2 * a2 + a3 * a3);
    #pragma unroll
    for (int m = 32; m >= 1; m >>= 1) v += __shfl_xor(v, m);
    const float rstd = rsqrtf(v * (1.0f / 256.0f) + 1e-5f);

    const float4 g  = *(const float4*)(g_msa  + c);
    const float4 bt = *(const float4*)(bt_msa + c);
    float4 o;
    o.x = a0 * rstd * g.x + bt.x;
    o.y = a1 * rstd * g.y + bt.y;
    o.z = a2 * rstd * g.z + bt.z;
    o.w = a3 * rstd * g.w + bt.w;
    *(float4*)(out_msa + base) = o;
}

extern "C" void kernel_launch(void* const* d_in, const int* in_sizes, int n_in,
                              void* d_out, int out_size, void* d_ws, size_t ws_size,
                              hipStream_t stream) {
    const int*   aatype        = (const int*)d_in[0];
    const int*   residue_index = (const int*)d_in[1];
    const int*   asym_id       = (const int*)d_in[2];
    const int*   entity_id     = (const int*)d_in[3];
    const int*   sym_id        = (const int*)d_in[4];
    const float* prev_pos      = (const float*)d_in[5];
    const float* prev_pair     = (const float*)d_in[6];
    const float* prev_msa      = (const float*)d_in[7];
    const float* w_dgram       = (const float*)d_in[8];
    const float* b_dgram       = (const float*)d_in[9];
    const float* g_pair        = (const float*)d_in[10];
    const float* bt_pair       = (const float*)d_in[11];
    const float* g_msa         = (const float*)d_in[12];
    const float* bt_msa        = (const float*)d_in[13];
    const float* w_rel         = (const float*)d_in[14];
    const float* b_rel         = (const float*)d_in[15];

    float* out_msa  = (float*)d_out;                       // [768,256] first
    float* out_pair = out_msa + (long)NRES * CMSA;         // then [768,768,128]

    msa_kernel<<<(NRES * 64 + 255) / 256, 256, 0, stream>>>(
        prev_msa, g_msa, bt_msa, out_msa);

    pair_kernel<<<NRES * 3, 256, 0, stream>>>(
        aatype, residue_index, asym_id, entity_id, sym_id,
        prev_pos, prev_pair,
        w_dgram, b_dgram, g_pair, bt_pair, w_rel, b_rel,
        out_pair);
}

// Round 6
// 517.255 us; speedup vs baseline: 1.0078x; 1.0078x over previous
//
#include <hip/hip_runtime.h>

#define NRES 768
#define CPAIR 128
#define CMSA 256
#define TPAD 132   // LDS table row stride: 128+4 floats -> consecutive rows
                   // shift by 4 banks so the 4 16-lane groups of a wave hit
                   // disjoint banks on ds_read_b128 (was 4-way conflict)

// 16-lane rotate-reduce step via DPP (row_ror:N within each 16-lane row).
template <int CTRL>
__device__ __forceinline__ float dpp_rot_add(float v) {
    const int r = __builtin_amdgcn_update_dpp(
        0, __float_as_int(v), CTRL, 0xF, 0xF, true);
    return v + __int_as_float(r);
}

// pair_kernel: one block (256 threads = 4 waves) handles 256 consecutive pairs
// within one row i. Grid = 768 rows x 3 segments.
//
// R6: R4 structure (simple unroll-2 loop, plain float4 stores — best measured)
// + padded LDS tables (TPAD=132) to kill cross-group bank conflicts.
__global__ __launch_bounds__(256) void pair_kernel(
    const int* __restrict__ aatype,
    const int* __restrict__ residue_index,
    const int* __restrict__ asym_id,
    const int* __restrict__ entity_id,
    const int* __restrict__ sym_id,
    const float* __restrict__ prev_pos,
    const float* __restrict__ prev_pair,
    const float* __restrict__ w_dgram,
    const float* __restrict__ b_dgram,
    const float* __restrict__ g_pair,
    const float* __restrict__ bt_pair,
    const float* __restrict__ w_rel,
    const float* __restrict__ b_rel,
    float* __restrict__ out_pair)
{
    __shared__ float Dtab[16][TPAD];
    __shared__ float Etab[6][TPAD];
    __shared__ unsigned short packs[256];

    const int tid = threadIdx.x;
    const int bx  = blockIdx.x;
    const int i   = bx / 3;                 // magic-mul div
    const int seg = bx - i * 3;
    const int j0  = seg * 256;

    // ---- stage distogram table (row 0 = zeros for bin==-1) ----
    for (int idx = tid; idx < 16 * 128; idx += 256) {
        const int r = idx >> 7, c = idx & 127;
        Dtab[r][c] = (r == 0) ? 0.0f : w_dgram[(r - 1) * 128 + c];
    }
    // ---- stage entity/chain table with constant bias vector folded in ----
    for (int idx = tid; idx < 6 * 128; idx += 256) {
        const int r = idx >> 7, c = idx & 127;
        const float cv = bt_pair[c] + b_dgram[c] + b_rel[c];
        const float wc = w_rel[(67 + r) * 128 + c];
        Etab[r][c] = cv + ((r < 5) ? (w_rel[66 * 128 + c] + wc) : wc);
    }

    // ---- per-pair packed indices: thread tid -> pair (i, j0+tid) ----
    {
        const int j  = j0 + tid;
        const int ai = (aatype[i] == 7) ? 1 : 3;   // GLY -> CA else CB
        const int aj = (aatype[j] == 7) ? 1 : 3;
        const float* pi = prev_pos + ((long)i * 37 + ai) * 3;
        const float* pj = prev_pos + ((long)j * 37 + aj) * 3;
        const float dx = pi[0] - pj[0];
        const float dy = pi[1] - pj[1];
        const float dz = pi[2] - pj[2];
        const float d2 = dx * dx + dy * dy + dz * dz;

        int bin = -1;
        #pragma unroll
        for (int b = 0; b < 15; ++b) {
            const float lo = 3.25f + 1.25f * (float)b;
            const float l2 = lo * lo;
            const float hi = lo + 1.25f;
            const float u2 = (b == 14) ? 1e8f : hi * hi;
            if (d2 > l2 && d2 < u2) bin = b;       // strict, matches reference
        }

        const bool asame = asym_id[i] == asym_id[j];
        int off = residue_index[i] - residue_index[j] + 32;
        off = min(max(off, 0), 64);
        const int p = asame ? off : 65;

        const bool esame = entity_id[i] == entity_id[j];
        int ch = sym_id[i] - sym_id[j] + 2;
        ch = min(max(ch, 0), 4);
        const int eidx = esame ? ch : 5;

        packs[tid] = (unsigned short)((bin + 1) | (p << 4) | (eidx << 11));
    }

    // ---- persistent per-lane channel vectors ----
    const int lane = tid & 63;
    const int wid  = tid >> 6;
    const int g    = lane >> 4;
    const int t    = lane & 15;
    const int c0   = t * 4;
    const int c1   = c0 + 64;

    const float4 gp0 = *(const float4*)(g_pair + c0);
    const float4 gp1 = *(const float4*)(g_pair + c1);

    __syncthreads();

    const float* rowp = prev_pair + ((long)i * NRES + j0) * CPAIR;
    float*       outp = out_pair + ((long)i * NRES + j0) * CPAIR;

    #pragma unroll 2
    for (int k = 0; k < 16; ++k) {
        const int pl = (wid << 6) | (k << 2) | g;      // pair within block
        const unsigned int pk = packs[pl];             // LDS broadcast in group
        const int bidx = pk & 15;
        const int p    = (pk >> 4) & 127;
        const int eidx = (pk >> 11) & 7;

        const float* xp = rowp + (long)pl * CPAIR;
        const float4 x0 = *(const float4*)(xp + c0);
        const float4 x1 = *(const float4*)(xp + c1);

        const float* wr = w_rel + p * 128;
        const float4 w0 = *(const float4*)(wr + c0);
        const float4 w1 = *(const float4*)(wr + c1);
        const float4 d0 = *(const float4*)(&Dtab[bidx][c0]);
        const float4 d1 = *(const float4*)(&Dtab[bidx][c1]);
        const float4 e0 = *(const float4*)(&Etab[eidx][c0]);
        const float4 e1 = *(const float4*)(&Etab[eidx][c1]);

        // one-pass stats: s = sum(x), q = sum(x^2); two independent DPP chains
        float s = ((x0.x + x0.y) + (x0.z + x0.w)) + ((x1.x + x1.y) + (x1.z + x1.w));
        float q = ((x0.x * x0.x + x0.y * x0.y) + (x0.z * x0.z + x0.w * x0.w)) +
                  ((x1.x * x1.x + x1.y * x1.y) + (x1.z * x1.z + x1.w * x1.w));
        s = dpp_rot_add<0x121>(s); q = dpp_rot_add<0x121>(q);  // ror 1
        s = dpp_rot_add<0x122>(s); q = dpp_rot_add<0x122>(q);  // ror 2
        s = dpp_rot_add<0x124>(s); q = dpp_rot_add<0x124>(q);  // ror 4
        s = dpp_rot_add<0x128>(s); q = dpp_rot_add<0x128>(q);  // ror 8

        const float mu = s * (1.0f / 128.0f);
        const float var = q * (1.0f / 128.0f) - mu * mu;
        const float rstd = rsqrtf(var + 1e-5f);

        const float v0 = x0.x - mu, v1 = x0.y - mu, v2 = x0.z - mu, v3 = x0.w - mu;
        const float v4 = x1.x - mu, v5 = x1.y - mu, v6 = x1.z - mu, v7 = x1.w - mu;

        float4 o0, o1;
        o0.x = v0 * rstd * gp0.x + (d0.x + w0.x + e0.x);
        o0.y = v1 * rstd * gp0.y + (d0.y + w0.y + e0.y);
        o0.z = v2 * rstd * gp0.z + (d0.z + w0.z + e0.z);
        o0.w = v3 * rstd * gp0.w + (d0.w + w0.w + e0.w);
        o1.x = v4 * rstd * gp1.x + (d1.x + w1.x + e1.x);
        o1.y = v5 * rstd * gp1.y + (d1.y + w1.y + e1.y);
        o1.z = v6 * rstd * gp1.z + (d1.z + w1.z + e1.z);
        o1.w = v7 * rstd * gp1.w + (d1.w + w1.w + e1.w);

        float* op = outp + (long)pl * CPAIR;
        *(float4*)(op + c0) = o0;
        *(float4*)(op + c1) = o1;
    }
}

// One wave64 per residue row; lane l holds channels 4l..4l+3 (float4).
__global__ __launch_bounds__(256) void msa_kernel(
    const float* __restrict__ prev_msa,
    const float* __restrict__ g_msa,
    const float* __restrict__ bt_msa,
    float* __restrict__ out_msa)
{
    const int lane = threadIdx.x & 63;
    const int row = (int)((blockIdx.x * blockDim.x + threadIdx.x) >> 6);
    if (row >= NRES) return;

    const int c = lane * 4;
    const long base = (long)row * CMSA + c;
    const float4 x = *(const float4*)(prev_msa + base);

    float s = (x.x + x.y) + (x.z + x.w);
    #pragma unroll
    for (int m = 32; m >= 1; m >>= 1) s += __shfl_xor(s, m);
    const float mu = s * (1.0f / 256.0f);

    const float a0 = x.x - mu, a1 = x.y - mu, a2 = x.z - mu, a3 = x.w - mu;
    float v = (a0 * a0 + a1 * a1) + (a2 * a2 + a3 * a3);
    #pragma unroll
    for (int m = 32; m >= 1; m >>= 1) v += __shfl_xor(v, m);
    const float rstd = rsqrtf(v * (1.0f / 256.0f) + 1e-5f);

    const float4 g  = *(const float4*)(g_msa  + c);
    const float4 bt = *(const float4*)(bt_msa + c);
    float4 o;
    o.x = a0 * rstd * g.x + bt.x;
    o.y = a1 * rstd * g.y + bt.y;
    o.z = a2 * rstd * g.z + bt.z;
    o.w = a3 * rstd * g.w + bt.w;
    *(float4*)(out_msa + base) = o;
}

extern "C" void kernel_launch(void* const* d_in, const int* in_sizes, int n_in,
                              void* d_out, int out_size, void* d_ws, size_t ws_size,
                              hipStream_t stream) {
    const int*   aatype        = (const int*)d_in[0];
    const int*   residue_index = (const int*)d_in[1];
    const int*   asym_id       = (const int*)d_in[2];
    const int*   entity_id     = (const int*)d_in[3];
    const int*   sym_id        = (const int*)d_in[4];
    const float* prev_pos      = (const float*)d_in[5];
    const float* prev_pair     = (const float*)d_in[6];
    const float* prev_msa      = (const float*)d_in[7];
    const float* w_dgram       = (const float*)d_in[8];
    const float* b_dgram       = (const float*)d_in[9];
    const float* g_pair        = (const float*)d_in[10];
    const float* bt_pair       = (const float*)d_in[11];
    const float* g_msa         = (const float*)d_in[12];
    const float* bt_msa        = (const float*)d_in[13];
    const float* w_rel         = (const float*)d_in[14];
    const float* b_rel         = (const float*)d_in[15];

    float* out_msa  = (float*)d_out;                       // [768,256] first
    float* out_pair = out_msa + (long)NRES * CMSA;         // then [768,768,128]

    msa_kernel<<<(NRES * 64 + 255) / 256, 256, 0, stream>>>(
        prev_msa, g_msa, bt_msa, out_msa);

    pair_kernel<<<NRES * 3, 256, 0, stream>>>(
        aatype, residue_index, asym_id, entity_id, sym_id,
        prev_pos, prev_pair,
        w_dgram, b_dgram, g_pair, bt_pair, w_rel, b_rel,
        out_pair);
}